// Round 2
// baseline (7502.795 us; speedup 1.0000x reference)
//
#include <hip/hip_runtime.h>
#include <hip/hip_bf16.h>

// Problem constants (B, I, D, J, C from reference)
#define B_ 32
#define I_ 2048
#define D_ 16
#define J_ 64
#define C_ 32

__device__ __forceinline__ float dot16(const float4* __restrict__ wp,
                                       float4 x0, float4 x1, float4 x2, float4 x3) {
  float4 a0 = wp[0], a1 = wp[1], a2 = wp[2], a3 = wp[3];
  float u = a0.x * x0.x + a0.y * x0.y + a0.z * x0.z + a0.w * x0.w;
  u += a1.x * x1.x + a1.y * x1.y + a1.z * x1.z + a1.w * x1.w;
  u += a2.x * x2.x + a2.y * x2.y + a2.z * x2.z + a2.w * x2.w;
  u += a3.x * x3.x + a3.y * x3.y + a3.z * x3.z + a3.w * x3.w;
  return u;
}

// One fused routing pass:
//   u = recompute u_hat from x,w (streaming w once)
//   if (!UNIFORM): b_new = (READB ? b_prev : 0) + v . u ; c = softmax_J(b_new)
//   else:          c = 1/J
//   s += c * u   (per-wave LDS partials -> one atomicAdd set per block)
// Wave layout: lane = h*32 + c (h = half, c = capsule-dim); lane handles j = 2k+h, k=0..31.
template <int UNIFORM, int READB, int WRITEB>
__global__ __launch_bounds__(256) void caps_pass(const float* __restrict__ x,
                                                 const float* __restrict__ w,
                                                 const float* __restrict__ vg,
                                                 float* __restrict__ bio,
                                                 float* __restrict__ sg) {
  __shared__ float s_acc[4][J_ * C_];
  const int tid = threadIdx.x;
  for (int idx = tid; idx < 4 * J_ * C_; idx += 256) ((float*)s_acc)[idx] = 0.f;
  __syncthreads();

  const int lane = tid & 63;
  const int wv = tid >> 6;
  const int b = blockIdx.y;
  const int h = lane >> 5;
  const int c = lane & 31;
  const int i0 = blockIdx.x * 64 + wv * 16;

  for (int ii = 0; ii < 16; ++ii) {
    const int i = i0 + ii;
    const float4* xp = (const float4*)(x + ((size_t)b * I_ + i) * D_);
    float4 x0 = xp[0], x1 = xp[1], x2 = xp[2], x3 = xp[3];

    float uk[32];
    float bk[32];

#pragma unroll
    for (int k = 0; k < 32; ++k) {
      const int j = 2 * k + h;
      const float4* wp = (const float4*)(w + (((size_t)j * I_ + i) * C_ + c) * D_);
      float u = dot16(wp, x0, x1, x2, x3);
      uk[k] = u;
      if (!UNIFORM) {
        // partial of v[b,j,:] . u[b,j,i,:] ; reduce over c (32 lanes in group)
        float p = vg[(b * J_ + j) * C_ + c] * u;
        p += __shfl_xor(p, 16, 32);
        p += __shfl_xor(p, 8, 32);
        p += __shfl_xor(p, 4, 32);
        p += __shfl_xor(p, 2, 32);
        p += __shfl_xor(p, 1, 32);
        bk[k] = p;  // all lanes in group h now hold dot for j=2k+h
      }
    }

    if (UNIFORM) {
#pragma unroll
      for (int k = 0; k < 32; ++k)
        s_acc[wv][(2 * k + h) * C_ + c] += uk[k] * (1.0f / (float)J_);
    } else {
      if (READB) {
        // coalesced read of the b-row (j = lane), redistribute via bpermute
        float breg = bio[((size_t)b * I_ + i) * J_ + lane];
#pragma unroll
        for (int k = 0; k < 32; ++k) bk[k] += __shfl(breg, 2 * k + h);
      }
      if (WRITEB) {
        // lane (h,c) is the designated writer for j = 2c+h; select bk[c] statically
        float bsel = bk[0];
#pragma unroll
        for (int k = 1; k < 32; ++k) bsel = (c == k) ? bk[k] : bsel;
        bio[((size_t)b * I_ + i) * J_ + 2 * c + h] = bsel;
      }
      // softmax over all 64 j
      float m = bk[0];
#pragma unroll
      for (int k = 1; k < 32; ++k) m = fmaxf(m, bk[k]);
      m = fmaxf(m, __shfl_xor(m, 32));  // combine across halves (other parity)
      float sum = 0.f;
#pragma unroll
      for (int k = 0; k < 32; ++k) {
        bk[k] = __expf(bk[k] - m);
        sum += bk[k];
      }
      sum += __shfl_xor(sum, 32);
      const float inv = 1.0f / sum;
#pragma unroll
      for (int k = 0; k < 32; ++k)
        s_acc[wv][(2 * k + h) * C_ + c] += bk[k] * inv * uk[k];
    }
  }

  __syncthreads();
  for (int jc = tid; jc < J_ * C_; jc += 256) {
    float t = s_acc[0][jc] + s_acc[1][jc] + s_acc[2][jc] + s_acc[3][jc];
    atomicAdd(&sg[(size_t)b * J_ * C_ + jc], t);
  }
}

// squash: v = s + EPS (elementwise); norm = sum(v*v); out = norm/(1+norm)/sqrt(norm) * v
__global__ __launch_bounds__(256) void caps_squash(const float* __restrict__ sg,
                                                   float* __restrict__ vg,
                                                   float* __restrict__ outg,
                                                   int write_out) {
  const int r = blockIdx.x * blockDim.x + threadIdx.x;  // row over B*J
  if (r >= B_ * J_) return;
  const float* sp = sg + (size_t)r * C_;
  float vals[C_];
  float norm = 0.f;
#pragma unroll
  for (int cc = 0; cc < C_; ++cc) {
    float t = sp[cc] + 1e-7f;
    vals[cc] = t;
    norm += t * t;
  }
  const float scale = norm / (1.0f + norm) / sqrtf(norm);
  float* vp = vg + (size_t)r * C_;
#pragma unroll
  for (int cc = 0; cc < C_; ++cc) vp[cc] = scale * vals[cc];
  if (write_out) {
    float* op = outg + (size_t)r * C_;
#pragma unroll
    for (int cc = 0; cc < C_; ++cc) op[cc] = scale * vals[cc];
  }
}

extern "C" void kernel_launch(void* const* d_in, const int* in_sizes, int n_in,
                              void* d_out, int out_size, void* d_ws, size_t ws_size,
                              hipStream_t stream) {
  const float* x = (const float*)d_in[0];   // [B, I, D]
  const float* w = (const float*)d_in[1];   // [J, I, C, D]
  float* out = (float*)d_out;               // [B, J, C]

  // Workspace layout (ws is re-poisoned each call; b is write-before-read, s is memset)
  float* b_ws = (float*)d_ws;                         // [B, I, J]   16 MiB
  float* s_ws = b_ws + (size_t)B_ * I_ * J_;          // [B, J, C]  256 KiB
  float* v_ws = s_ws + (size_t)B_ * J_ * C_;          // [B, J, C]  256 KiB

  const size_t s_bytes = (size_t)B_ * J_ * C_ * sizeof(float);
  dim3 grid(I_ / 64, B_), blk(256);
  dim3 sgrid((B_ * J_ + 255) / 256), sblk(256);

  // it 0: c uniform, s0, v0  (b-update folded into pass 1)
  hipMemsetAsync(s_ws, 0, s_bytes, stream);
  caps_pass<1, 0, 0><<<grid, blk, 0, stream>>>(x, w, v_ws, b_ws, s_ws);
  caps_squash<<<sgrid, sblk, 0, stream>>>(s_ws, v_ws, out, 0);

  // it 1: b1 = v0.u (no prior b), softmax, s1, v1
  hipMemsetAsync(s_ws, 0, s_bytes, stream);
  caps_pass<0, 0, 1><<<grid, blk, 0, stream>>>(x, w, v_ws, b_ws, s_ws);
  caps_squash<<<sgrid, sblk, 0, stream>>>(s_ws, v_ws, out, 0);

  // it 2: b2 = b1 + v1.u
  hipMemsetAsync(s_ws, 0, s_bytes, stream);
  caps_pass<0, 1, 1><<<grid, blk, 0, stream>>>(x, w, v_ws, b_ws, s_ws);
  caps_squash<<<sgrid, sblk, 0, stream>>>(s_ws, v_ws, out, 0);

  // it 3: b3 = b2 + v2.u
  hipMemsetAsync(s_ws, 0, s_bytes, stream);
  caps_pass<0, 1, 1><<<grid, blk, 0, stream>>>(x, w, v_ws, b_ws, s_ws);
  caps_squash<<<sgrid, sblk, 0, stream>>>(s_ws, v_ws, out, 0);

  // it 4: b4 = b3 + v3.u (no write-back), softmax, s4, v4 -> output
  hipMemsetAsync(s_ws, 0, s_bytes, stream);
  caps_pass<0, 1, 0><<<grid, blk, 0, stream>>>(x, w, v_ws, b_ws, s_ws);
  caps_squash<<<sgrid, sblk, 0, stream>>>(s_ws, v_ws, out, 1);
}

// Round 5
// 806.316 us; speedup vs baseline: 9.3050x; 9.3050x over previous
//
#include <hip/hip_runtime.h>
#include <hip/hip_bf16.h>

#define B_ 32
#define I_ 2048
#define D_ 16
#define J_ 64
#define C_ 32

typedef float f32x16 __attribute__((ext_vector_type(16)));
typedef float f32x4a __attribute__((ext_vector_type(4)));
typedef short bf16x8 __attribute__((ext_vector_type(8)));

union BF8 { unsigned u[4]; bf16x8 v; };

__device__ __forceinline__ float bf2f(unsigned short u) {
  unsigned v = ((unsigned)u) << 16;
  float f;
  __builtin_memcpy(&f, &v, 4);
  return f;
}
__device__ __forceinline__ unsigned short f2bf(float f) {
  unsigned u;
  __builtin_memcpy(&u, &f, 4);
  u += 0x7FFFu + ((u >> 16) & 1u);  // RNE
  return (unsigned short)(u >> 16);
}
__device__ __forceinline__ unsigned pk2(float lo, float hi) {
  return (unsigned)f2bf(lo) | ((unsigned)f2bf(hi) << 16);
}

// ---------------- prepass: w f32 -> w_bf [j][i][c][d] and w2 [j][i][d][c] ----------------
__global__ __launch_bounds__(256) void prep_w(const float* __restrict__ w,
                                              unsigned short* __restrict__ w_bf,
                                              unsigned short* __restrict__ w2) {
  __shared__ float tr[16 * 33];
  const int tid = threadIdx.x;
  const int j = blockIdx.y, i0 = blockIdx.x * 16;
  for (int ii = 0; ii < 16; ++ii) {
    size_t base = ((size_t)j * I_ + i0 + ii) * 512;
    float2 v2 = *(const float2*)(w + base + 2 * tid);
    ((unsigned*)(w_bf + base))[tid] = pk2(v2.x, v2.y);
    int c = (2 * tid) >> 4, d = (2 * tid) & 15;  // elem e=2t = c*16+d (d even)
    tr[d * 33 + c] = v2.x;
    tr[(d + 1) * 33 + c] = v2.y;
    __syncthreads();
    int d2 = (2 * tid) >> 5, c2 = (2 * tid) & 31;  // out elem o=2t = d2*32+c2 (c2 even)
    ((unsigned*)(w2 + base))[tid] = pk2(tr[d2 * 33 + c2], tr[d2 * 33 + c2 + 1]);
    __syncthreads();
  }
}

// ---------------- prepass: x4 [i][half][b][8] bf16 (A-frag layout for pass_s) ----------------
__global__ __launch_bounds__(256) void prep_x4(const float* __restrict__ x,
                                               unsigned short* __restrict__ x4) {
  int g = blockIdx.x * 256 + threadIdx.x;  // 131072 = I*2*B
  int b = g & 31, o2 = (g >> 5) & 1, i = g >> 6;
  const float* xp = x + ((size_t)b * I_ + i) * D_ + o2 * 8;
  float4 a = *(const float4*)xp;
  float4 c = *(const float4*)(xp + 4);
  BF8 o;
  o.u[0] = pk2(a.x, a.y);
  o.u[1] = pk2(a.z, a.w);
  o.u[2] = pk2(c.x, c.y);
  o.u[3] = pk2(c.z, c.w);
  ((bf16x8*)x4)[g] = o.v;
}

// ---------------- pass A: bdot + (accumulate b) + softmax -> c_bf ----------------
// block: one i-pair (i0, i0+1), all j, all b. 4 waves x 16 j each.
// WV^T[(i,d), b] = W2_j[(i,d), c] @ V^T[c, b]  (mfma 32x32x16, 2 k-steps over c)
template <int ACCUM, int WRITEB>
__global__ __launch_bounds__(256) void pass_bdot(const float* __restrict__ x,
                                                 const unsigned short* __restrict__ w2,
                                                 const float* __restrict__ vg,
                                                 float* __restrict__ b_run,
                                                 unsigned short* __restrict__ c_bf) {
  __shared__ float x_lds[32 * 36];
  __shared__ float bd[64 * 64];            // [j][ii*32+b]
  __shared__ unsigned short c_l[64 * 64];  // [j][ii*32+b]
  const int tid = threadIdx.x;
  const int i0 = blockIdx.x * 2;

  {  // stage x[b][i0..i0+1][0..15] -> x_lds[b][i_loc*16+d] (pad 36)
    int b = tid >> 3, idx = (tid & 7) * 4;
    int i_loc = idx >> 4, d = idx & 15;
    float4 v4 = *(const float4*)(x + ((size_t)b * I_ + i0 + i_loc) * D_ + d);
    *(float4*)(x_lds + b * 36 + idx) = v4;
  }
  __syncthreads();

  const int lane = tid & 63;
  const int wv = tid >> 6;
  const int ml = lane & 31;  // A: m=(i_loc,d) index; B: n=b; C/D col=b
  const int h = lane >> 5;

  // x regs for the d-reduction: rows (r&3)+8*(r>>2)+4h at column b=ml
  f32x4a xr0 = *(const f32x4a*)(x_lds + ml * 36 + 4 * h);
  f32x4a xr1 = *(const f32x4a*)(x_lds + ml * 36 + 8 + 4 * h);
  f32x4a xr2 = *(const f32x4a*)(x_lds + ml * 36 + 16 + 4 * h);
  f32x4a xr3 = *(const f32x4a*)(x_lds + ml * 36 + 24 + 4 * h);

  for (int j = wv; j < 64; j += 4) {
    BF8 Bf0, Bf1, Af0, Af1;
    // B-frag: V^T[c, b]: lane n=ml -> b ; k = h*8+r -> c (+16 per kstep)
    {
      const float* vp = vg + ((size_t)ml * J_ + j) * C_ + h * 8;
      float4 a = *(const float4*)vp;
      float4 b4 = *(const float4*)(vp + 4);
      Bf0.u[0] = pk2(a.x, a.y); Bf0.u[1] = pk2(a.z, a.w);
      Bf0.u[2] = pk2(b4.x, b4.y); Bf0.u[3] = pk2(b4.z, b4.w);
      const float* vp1 = vp + 16;
      float4 a1 = *(const float4*)vp1;
      float4 b5 = *(const float4*)(vp1 + 4);
      Bf1.u[0] = pk2(a1.x, a1.y); Bf1.u[1] = pk2(a1.z, a1.w);
      Bf1.u[2] = pk2(b5.x, b5.y); Bf1.u[3] = pk2(b5.z, b5.w);
    }
    // A-frag: W2_j[(i,d), c]: m=ml -> (i = i0+(ml>>4), d = ml&15); k = c
    {
      const unsigned short* wp =
          w2 + (((size_t)j * I_ + i0 + (ml >> 4)) * 16 + (ml & 15)) * 32 + h * 8;
      Af0.v = *(const bf16x8*)wp;
      Af1.v = *(const bf16x8*)(wp + 16);
    }
    f32x16 acc = 0.0f;
    acc = __builtin_amdgcn_mfma_f32_32x32x16_bf16(Af0.v, Bf0.v, acc, 0, 0, 0);
    acc = __builtin_amdgcn_mfma_f32_32x32x16_bf16(Af1.v, Bf1.v, acc, 0, 0, 0);
    // acc[r] = WV^T[row, b=ml], row = (r&3)+8*(r>>2)+4h = i_loc*16 + d
    float s0 = 0.f, s1 = 0.f;
#pragma unroll
    for (int r = 0; r < 4; ++r) s0 += acc[r] * xr0[r];
#pragma unroll
    for (int r = 0; r < 4; ++r) s0 += acc[4 + r] * xr1[r];
#pragma unroll
    for (int r = 0; r < 4; ++r) s1 += acc[8 + r] * xr2[r];
#pragma unroll
    for (int r = 0; r < 4; ++r) s1 += acc[12 + r] * xr3[r];
    s0 += __shfl_xor(s0, 32);
    s1 += __shfl_xor(s1, 32);
    bd[j * 64 + h * 32 + ml] = h ? s1 : s0;  // bdot[b=ml, i=i0+h]
  }
  __syncthreads();

  if (ACCUM) {
#pragma unroll 4
    for (int rep = 0; rep < 16; ++rep) {
      int idx = rep * 256 + tid;
      int j = idx >> 6, q = idx & 63, ii = q >> 5, b = q & 31;
      bd[idx] += b_run[((size_t)j * I_ + i0 + ii) * 32 + b];
    }
    __syncthreads();
  }
  if (WRITEB) {
#pragma unroll 4
    for (int rep = 0; rep < 16; ++rep) {
      int idx = rep * 256 + tid;
      int j = idx >> 6, q = idx & 63, ii = q >> 5, b = q & 31;
      b_run[((size_t)j * I_ + i0 + ii) * 32 + b] = bd[idx];
    }
  }
  __syncthreads();

  if (tid < 64) {  // softmax over j for (ii = tid>>5, b = tid&31)
    int q = tid;
    float m = -1e30f;
    for (int j = 0; j < 64; ++j) m = fmaxf(m, bd[j * 64 + q]);
    float sum = 0.f;
    for (int j = 0; j < 64; ++j) {
      float e = __expf(bd[j * 64 + q] - m);
      bd[j * 64 + q] = e;
      sum += e;
    }
    float inv = 1.0f / sum;
    for (int j = 0; j < 64; ++j) c_l[j * 64 + q] = f2bf(bd[j * 64 + q] * inv);
  }
  __syncthreads();

  // cooperative write c_bf[j][i][b] (2048 u32)
#pragma unroll 4
  for (int rep = 0; rep < 8; ++rep) {
    int idx = rep * 256 + tid;
    int j = idx >> 5, q2 = idx & 31;
    unsigned val = (unsigned)c_l[j * 64 + 2 * q2] | ((unsigned)c_l[j * 64 + 2 * q2 + 1] << 16);
    *(unsigned*)(c_bf + ((size_t)j * I_ + i0) * 32 + 2 * q2) = val;
  }
}

// ---------------- pass B: partial S_j[b,c] per (slice, j) -- NO atomics ----------------
template <int UNIFORM>
__global__ __launch_bounds__(256) void pass_s(const unsigned short* __restrict__ w_bf,
                                              const unsigned short* __restrict__ x4,
                                              const unsigned short* __restrict__ c_bf,
                                              float* __restrict__ gpart) {
  __shared__ float s_part[4][1024];  // [wave][b*32+c]
  const int tid = threadIdx.x, lane = tid & 63, wv = tid >> 6;
  const int j = blockIdx.y;
  const int slice = blockIdx.x;
  const int ibase = slice * 128 + wv * 32;
  const int ml = lane & 31, h = lane >> 5;
  f32x16 acc = 0.0f;
#pragma unroll 4
  for (int ii = 0; ii < 32; ++ii) {
    int i = ibase + ii;
    // A-frag: y[b=ml, d = h*8 + r] = c[b,j,i] * x[b,i,d]
    BF8 xa;
    xa.v = *(const bf16x8*)(x4 + (((size_t)i * 2 + h) * 32 + ml) * 8);
    float cf;
    if (UNIFORM) cf = 1.0f / 64.0f;
    else cf = bf2f(c_bf[((size_t)j * I_ + i) * 32 + ml]);
    BF8 ya;
#pragma unroll
    for (int p = 0; p < 4; ++p) {
      unsigned short lo16 = (unsigned short)(xa.u[p] & 0xFFFFu);
      unsigned short hi16 = (unsigned short)(xa.u[p] >> 16);
      ya.u[p] = pk2(bf2f(lo16) * cf, bf2f(hi16) * cf);
    }
    // B-frag: W_j[(i,d), c]: n=ml -> c ; k = h*8+r -> d
    BF8 wb;
    wb.v = *(const bf16x8*)(w_bf + ((size_t)j * I_ + i) * 512 + ml * 16 + h * 8);
    acc = __builtin_amdgcn_mfma_f32_32x32x16_bf16(ya.v, wb.v, acc, 0, 0, 0);
  }
  // acc[r] = S[b = (r&3)+8*(r>>2)+4h, c = ml] -> LDS, then deterministic block reduce
#pragma unroll
  for (int r = 0; r < 16; ++r) {
    int b = (r & 3) + 8 * (r >> 2) + 4 * h;
    s_part[wv][b * 32 + ml] = acc[r];
  }
  __syncthreads();
#pragma unroll
  for (int q = 0; q < 4; ++q) {
    int idx = q * 256 + tid;  // idx = b*32+c
    float t = s_part[0][idx] + s_part[1][idx] + s_part[2][idx] + s_part[3][idx];
    int b = idx >> 5, c = idx & 31;
    gpart[(((size_t)slice * B_ + b) * J_ + j) * C_ + c] = t;
  }
}

// ---------------- deterministic reduce over slices + squash (fused) ----------------
__global__ __launch_bounds__(256) void reduce_squash(const float* __restrict__ gpart,
                                                     float* __restrict__ vg,
                                                     float* __restrict__ outg,
                                                     int write_out) {
  const int gid = blockIdx.x * 256 + threadIdx.x;  // over B*J*C = 65536
  float sum = 0.f;
#pragma unroll
  for (int s = 0; s < 16; ++s) sum += gpart[(size_t)s * (B_ * J_ * C_) + gid];
  float t = sum + 1e-7f;
  float sq = t * t;
#pragma unroll
  for (int m = 16; m >= 1; m >>= 1) sq += __shfl_xor(sq, m);  // norm over c-group of 32
  const float scale = sq / (1.0f + sq) / sqrtf(sq);
  vg[gid] = scale * t;
  if (write_out) outg[gid] = scale * t;
}

// ---------------- squash (fallback path only) ----------------
__global__ __launch_bounds__(256) void caps_squash(const float* __restrict__ sg,
                                                   float* __restrict__ vg,
                                                   float* __restrict__ outg,
                                                   int write_out) {
  const int r = blockIdx.x * blockDim.x + threadIdx.x;
  if (r >= B_ * J_) return;
  const float* sp = sg + (size_t)r * C_;
  float vals[C_];
  float norm = 0.f;
#pragma unroll
  for (int cc = 0; cc < C_; ++cc) {
    float t = sp[cc] + 1e-7f;
    vals[cc] = t;
    norm += t * t;
  }
  const float scale = norm / (1.0f + norm) / sqrtf(norm);
  float* vp = vg + (size_t)r * C_;
#pragma unroll
  for (int cc = 0; cc < C_; ++cc) vp[cc] = scale * vals[cc];
  if (write_out) {
    float* op = outg + (size_t)r * C_;
#pragma unroll
    for (int cc = 0; cc < C_; ++cc) op[cc] = scale * vals[cc];
  }
}

// ================= fallback (round-2 proven) path =================
__device__ __forceinline__ float dot16(const float4* __restrict__ wp,
                                       float4 x0, float4 x1, float4 x2, float4 x3) {
  float4 a0 = wp[0], a1 = wp[1], a2 = wp[2], a3 = wp[3];
  float u = a0.x * x0.x + a0.y * x0.y + a0.z * x0.z + a0.w * x0.w;
  u += a1.x * x1.x + a1.y * x1.y + a1.z * x1.z + a1.w * x1.w;
  u += a2.x * x2.x + a2.y * x2.y + a2.z * x2.z + a2.w * x2.w;
  u += a3.x * x3.x + a3.y * x3.y + a3.z * x3.z + a3.w * x3.w;
  return u;
}

template <int UNIFORM, int READB, int WRITEB>
__global__ __launch_bounds__(256) void caps_pass(const float* __restrict__ x,
                                                 const float* __restrict__ w,
                                                 const float* __restrict__ vg,
                                                 float* __restrict__ bio,
                                                 float* __restrict__ sg) {
  __shared__ float s_acc[4][J_ * C_];
  const int tid = threadIdx.x;
  for (int idx = tid; idx < 4 * J_ * C_; idx += 256) ((float*)s_acc)[idx] = 0.f;
  __syncthreads();
  const int lane = tid & 63;
  const int wv = tid >> 6;
  const int b = blockIdx.y;
  const int h = lane >> 5;
  const int c = lane & 31;
  const int i0 = blockIdx.x * 64 + wv * 16;
  for (int ii = 0; ii < 16; ++ii) {
    const int i = i0 + ii;
    const float4* xp = (const float4*)(x + ((size_t)b * I_ + i) * D_);
    float4 x0 = xp[0], x1 = xp[1], x2 = xp[2], x3 = xp[3];
    float uk[32];
    float bk[32];
#pragma unroll
    for (int k = 0; k < 32; ++k) {
      const int j = 2 * k + h;
      const float4* wp = (const float4*)(w + (((size_t)j * I_ + i) * C_ + c) * D_);
      float u = dot16(wp, x0, x1, x2, x3);
      uk[k] = u;
      if (!UNIFORM) {
        float p = vg[(b * J_ + j) * C_ + c] * u;
        p += __shfl_xor(p, 16, 32);
        p += __shfl_xor(p, 8, 32);
        p += __shfl_xor(p, 4, 32);
        p += __shfl_xor(p, 2, 32);
        p += __shfl_xor(p, 1, 32);
        bk[k] = p;
      }
    }
    if (UNIFORM) {
#pragma unroll
      for (int k = 0; k < 32; ++k)
        s_acc[wv][(2 * k + h) * C_ + c] += uk[k] * (1.0f / (float)J_);
    } else {
      if (READB) {
        float breg = bio[((size_t)b * I_ + i) * J_ + lane];
#pragma unroll
        for (int k = 0; k < 32; ++k) bk[k] += __shfl(breg, 2 * k + h);
      }
      if (WRITEB) {
        float bsel = bk[0];
#pragma unroll
        for (int k = 1; k < 32; ++k) bsel = (c == k) ? bk[k] : bsel;
        bio[((size_t)b * I_ + i) * J_ + 2 * c + h] = bsel;
      }
      float m = bk[0];
#pragma unroll
      for (int k = 1; k < 32; ++k) m = fmaxf(m, bk[k]);
      m = fmaxf(m, __shfl_xor(m, 32));
      float sum = 0.f;
#pragma unroll
      for (int k = 0; k < 32; ++k) {
        bk[k] = __expf(bk[k] - m);
        sum += bk[k];
      }
      sum += __shfl_xor(sum, 32);
      const float inv = 1.0f / sum;
#pragma unroll
      for (int k = 0; k < 32; ++k)
        s_acc[wv][(2 * k + h) * C_ + c] += bk[k] * inv * uk[k];
    }
  }
  __syncthreads();
  for (int jc = tid; jc < J_ * C_; jc += 256) {
    float t = s_acc[0][jc] + s_acc[1][jc] + s_acc[2][jc] + s_acc[3][jc];
    atomicAdd(&sg[(size_t)b * J_ * C_ + jc], t);
  }
}

extern "C" void kernel_launch(void* const* d_in, const int* in_sizes, int n_in,
                              void* d_out, int out_size, void* d_ws, size_t ws_size,
                              hipStream_t stream) {
  const float* x = (const float*)d_in[0];  // [B, I, D]
  const float* w = (const float*)d_in[1];  // [J, I, C, D]
  float* out = (float*)d_out;              // [B, J, C]

  const size_t SZ_WBF = (size_t)J_ * I_ * C_ * D_ * 2;   // 128 MiB
  const size_t SZ_W2 = SZ_WBF;                           // 128 MiB
  const size_t SZ_X4 = (size_t)B_ * I_ * D_ * 2;         // 2 MiB
  const size_t SZ_CBF = (size_t)J_ * I_ * B_ * 2;        // 8 MiB
  const size_t SZ_BRUN = (size_t)J_ * I_ * B_ * 4;       // 16 MiB
  const size_t SZ_GP = (size_t)16 * B_ * J_ * C_ * 4;    // 4 MiB
  const size_t SZ_V = (size_t)B_ * J_ * C_ * 4;          // 256 KiB
  const size_t NEED = SZ_WBF + SZ_W2 + SZ_X4 + SZ_CBF + SZ_BRUN + SZ_GP + SZ_V;

  if (ws_size >= NEED) {
    char* p = (char*)d_ws;
    unsigned short* w_bf = (unsigned short*)p;  p += SZ_WBF;
    unsigned short* w2 = (unsigned short*)p;    p += SZ_W2;
    unsigned short* x4 = (unsigned short*)p;    p += SZ_X4;
    unsigned short* c_bf = (unsigned short*)p;  p += SZ_CBF;
    float* b_run = (float*)p;                   p += SZ_BRUN;
    float* gpart = (float*)p;                   p += SZ_GP;
    float* v_ws = (float*)p;

    prep_w<<<dim3(I_ / 16, J_), 256, 0, stream>>>(w, w_bf, w2);
    prep_x4<<<dim3((B_ * I_ * 2) / 256), 256, 0, stream>>>(x, x4);

    dim3 agrid(I_ / 2), bgrid(I_ / 128, J_), rgrid((B_ * J_ * C_) / 256);

    // it 0: uniform c
    pass_s<1><<<bgrid, 256, 0, stream>>>(w_bf, x4, c_bf, gpart);
    reduce_squash<<<rgrid, 256, 0, stream>>>(gpart, v_ws, out, 0);
    // it 1: b1 = v0.u (no prior b)
    pass_bdot<0, 1><<<agrid, 256, 0, stream>>>(x, w2, v_ws, b_run, c_bf);
    pass_s<0><<<bgrid, 256, 0, stream>>>(w_bf, x4, c_bf, gpart);
    reduce_squash<<<rgrid, 256, 0, stream>>>(gpart, v_ws, out, 0);
    // it 2
    pass_bdot<1, 1><<<agrid, 256, 0, stream>>>(x, w2, v_ws, b_run, c_bf);
    pass_s<0><<<bgrid, 256, 0, stream>>>(w_bf, x4, c_bf, gpart);
    reduce_squash<<<rgrid, 256, 0, stream>>>(gpart, v_ws, out, 0);
    // it 3
    pass_bdot<1, 1><<<agrid, 256, 0, stream>>>(x, w2, v_ws, b_run, c_bf);
    pass_s<0><<<bgrid, 256, 0, stream>>>(w_bf, x4, c_bf, gpart);
    reduce_squash<<<rgrid, 256, 0, stream>>>(gpart, v_ws, out, 0);
    // it 4 (no b write-back; write output)
    pass_bdot<1, 0><<<agrid, 256, 0, stream>>>(x, w2, v_ws, b_run, c_bf);
    pass_s<0><<<bgrid, 256, 0, stream>>>(w_bf, x4, c_bf, gpart);
    reduce_squash<<<rgrid, 256, 0, stream>>>(gpart, v_ws, out, 1);
  } else {
    // fallback: round-2 proven path (~7.5 ms but correct)
    float* b_ws = (float*)d_ws;
    float* s_ws = b_ws + (size_t)B_ * I_ * J_;
    float* v_ws = s_ws + (size_t)B_ * J_ * C_;
    const size_t s_bytes = (size_t)B_ * J_ * C_ * sizeof(float);
    dim3 grid(I_ / 64, B_), blk(256);
    dim3 sgrid((B_ * J_ + 255) / 256), sblk(256);

    hipMemsetAsync(s_ws, 0, s_bytes, stream);
    caps_pass<1, 0, 0><<<grid, blk, 0, stream>>>(x, w, v_ws, b_ws, s_ws);
    caps_squash<<<sgrid, sblk, 0, stream>>>(s_ws, v_ws, out, 0);
    hipMemsetAsync(s_ws, 0, s_bytes, stream);
    caps_pass<0, 0, 1><<<grid, blk, 0, stream>>>(x, w, v_ws, b_ws, s_ws);
    caps_squash<<<sgrid, sblk, 0, stream>>>(s_ws, v_ws, out, 0);
    hipMemsetAsync(s_ws, 0, s_bytes, stream);
    caps_pass<0, 1, 1><<<grid, blk, 0, stream>>>(x, w, v_ws, b_ws, s_ws);
    caps_squash<<<sgrid, sblk, 0, stream>>>(s_ws, v_ws, out, 0);
    hipMemsetAsync(s_ws, 0, s_bytes, stream);
    caps_pass<0, 1, 1><<<grid, blk, 0, stream>>>(x, w, v_ws, b_ws, s_ws);
    caps_squash<<<sgrid, sblk, 0, stream>>>(s_ws, v_ws, out, 0);
    hipMemsetAsync(s_ws, 0, s_bytes, stream);
    caps_pass<0, 1, 0><<<grid, blk, 0, stream>>>(x, w, v_ws, b_ws, s_ws);
    caps_squash<<<sgrid, sblk, 0, stream>>>(s_ws, v_ws, out, 1);
  }
}

// Round 6
// 730.010 us; speedup vs baseline: 10.2777x; 1.1045x over previous
//
#include <hip/hip_runtime.h>
#include <hip/hip_bf16.h>

#define B_ 32
#define I_ 2048
#define D_ 16
#define J_ 64
#define C_ 32

typedef float f32x16 __attribute__((ext_vector_type(16)));
typedef float f32x4a __attribute__((ext_vector_type(4)));
typedef short bf16x8 __attribute__((ext_vector_type(8)));

union BF8 { unsigned u[4]; bf16x8 v; };

__device__ __forceinline__ unsigned cvtpk(float lo, float hi) {
  unsigned r;
  asm volatile("v_cvt_pk_bf16_f32 %0, %1, %2" : "=v"(r) : "v"(lo), "v"(hi));
  return r;
}
__device__ __forceinline__ float asf(unsigned u) {
  float f;
  __builtin_memcpy(&f, &u, 4);
  return f;
}
__device__ __forceinline__ float bf2f(unsigned short u) { return asf(((unsigned)u) << 16); }
__device__ __forceinline__ unsigned short f2bf(float f) {
  unsigned u;
  __builtin_memcpy(&u, &f, 4);
  u += 0x7FFFu + ((u >> 16) & 1u);  // RNE
  return (unsigned short)(u >> 16);
}

// ---------------- prepass: w f32 -> w_bf [j][i][c][d] and w2 [j][i][d][c] ----------------
__global__ __launch_bounds__(256) void prep_w(const float* __restrict__ w,
                                              unsigned short* __restrict__ w_bf,
                                              unsigned short* __restrict__ w2) {
  __shared__ float tr[16 * 33];
  const int tid = threadIdx.x;
  const int j = blockIdx.y, i0 = blockIdx.x * 16;
  for (int ii = 0; ii < 16; ++ii) {
    size_t base = ((size_t)j * I_ + i0 + ii) * 512;
    float2 v2 = *(const float2*)(w + base + 2 * tid);
    ((unsigned*)(w_bf + base))[tid] = cvtpk(v2.x, v2.y);
    int c = (2 * tid) >> 4, d = (2 * tid) & 15;  // elem e=2t = c*16+d (d even)
    tr[d * 33 + c] = v2.x;
    tr[(d + 1) * 33 + c] = v2.y;
    __syncthreads();
    int d2 = (2 * tid) >> 5, c2 = (2 * tid) & 31;  // out elem o=2t = d2*32+c2 (c2 even)
    ((unsigned*)(w2 + base))[tid] = cvtpk(tr[d2 * 33 + c2], tr[d2 * 33 + c2 + 1]);
    __syncthreads();
  }
}

// ---------------- prepass: x4 [i][half][b][8] bf16 (A-frag layout for pass_s) ----------------
__global__ __launch_bounds__(256) void prep_x4(const float* __restrict__ x,
                                               unsigned short* __restrict__ x4) {
  int g = blockIdx.x * 256 + threadIdx.x;  // 131072 = I*2*B
  int b = g & 31, o2 = (g >> 5) & 1, i = g >> 6;
  const float* xp = x + ((size_t)b * I_ + i) * D_ + o2 * 8;
  float4 a = *(const float4*)xp;
  float4 c = *(const float4*)(xp + 4);
  BF8 o;
  o.u[0] = cvtpk(a.x, a.y);
  o.u[1] = cvtpk(a.z, a.w);
  o.u[2] = cvtpk(c.x, c.y);
  o.u[3] = cvtpk(c.z, c.w);
  ((bf16x8*)x4)[g] = o.v;
}

// ---------------- pass A: bdot + (accumulate b) + softmax -> c_bf ----------------
// block: one i-pair (i0, i0+1), all j, all b. 4 waves x 16 j each (2 batches of 8 j).
// WV^T[(i,d), b] = W2_j[(i,d), c] @ V^T[c, b]  (mfma 32x32x16, 2 k-steps over c)
template <int ACCUM, int WRITEB>
__global__ __launch_bounds__(256) void pass_bdot(const float* __restrict__ x,
                                                 const unsigned short* __restrict__ w2,
                                                 const unsigned short* __restrict__ v_bf,
                                                 float* __restrict__ b_run,
                                                 unsigned short* __restrict__ c_bf) {
  __shared__ float x_lds[32 * 36];
  __shared__ float bd[64 * 64];            // [j][ii*32+b]
  __shared__ unsigned short c_l[64 * 64];  // [j][ii*32+b]
  __shared__ float pm[4][64], ps[4][64];
  const int tid = threadIdx.x;
  const int i0 = blockIdx.x * 2;

  {  // stage x[b][i0..i0+1][0..15] -> x_lds[b][i_loc*16+d] (pad 36)
    int b = tid >> 3, idx = (tid & 7) * 4;
    int i_loc = idx >> 4, d = idx & 15;
    float4 v4 = *(const float4*)(x + ((size_t)b * I_ + i0 + i_loc) * D_ + d);
    *(float4*)(x_lds + b * 36 + idx) = v4;
  }
  __syncthreads();

  const int lane = tid & 63;
  const int wv = tid >> 6;
  const int ml = lane & 31;  // A: m=(i_loc,d); B: n=b; C/D col=b
  const int h = lane >> 5;

  // x regs for the d-reduction: rows (r&3)+8*(r>>2)+4h at column b=ml
  f32x4a xr0 = *(const f32x4a*)(x_lds + ml * 36 + 4 * h);
  f32x4a xr1 = *(const f32x4a*)(x_lds + ml * 36 + 8 + 4 * h);
  f32x4a xr2 = *(const f32x4a*)(x_lds + ml * 36 + 16 + 4 * h);
  f32x4a xr3 = *(const f32x4a*)(x_lds + ml * 36 + 24 + 4 * h);

  // per-lane invariant base addresses
  const unsigned short* wbase = w2 + ((size_t)(i0 + (ml >> 4)) * 16 + (ml & 15)) * 32 + h * 8;
  const unsigned short* vbase = v_bf + (size_t)ml * (J_ * C_) + h * 8;

#pragma unroll
  for (int half = 0; half < 2; ++half) {
    // batch-load 8 j's A-frags (w2: HBM stream) -> max loads in flight
    BF8 Aw[8][2];
#pragma unroll
    for (int t = 0; t < 8; ++t) {
      const int j = wv + (half * 8 + t) * 4;
      const unsigned short* wp = wbase + (size_t)j * (I_ * 512);
      Aw[t][0].v = *(const bf16x8*)wp;
      Aw[t][1].v = *(const bf16x8*)(wp + 16);
    }
#pragma unroll
    for (int t = 0; t < 8; ++t) {
      const int j = wv + (half * 8 + t) * 4;
      const unsigned short* vp = vbase + j * C_;
      BF8 Bv0, Bv1;
      Bv0.v = *(const bf16x8*)vp;
      Bv1.v = *(const bf16x8*)(vp + 16);
      f32x16 acc = 0.0f;
      acc = __builtin_amdgcn_mfma_f32_32x32x16_bf16(Aw[t][0].v, Bv0.v, acc, 0, 0, 0);
      acc = __builtin_amdgcn_mfma_f32_32x32x16_bf16(Aw[t][1].v, Bv1.v, acc, 0, 0, 0);
      // acc[r] = WV^T[row=i_loc*16+d, b=ml], row = (r&3)+8*(r>>2)+4h
      float s0 = 0.f, s1 = 0.f;
#pragma unroll
      for (int r = 0; r < 4; ++r) s0 += acc[r] * xr0[r];
#pragma unroll
      for (int r = 0; r < 4; ++r) s0 += acc[4 + r] * xr1[r];
#pragma unroll
      for (int r = 0; r < 4; ++r) s1 += acc[8 + r] * xr2[r];
#pragma unroll
      for (int r = 0; r < 4; ++r) s1 += acc[12 + r] * xr3[r];
      s0 += __shfl_xor(s0, 32);
      s1 += __shfl_xor(s1, 32);
      bd[j * 64 + h * 32 + ml] = h ? s1 : s0;  // bdot[b=ml, i=i0+h]
    }
  }
  __syncthreads();

  if (ACCUM) {
#pragma unroll 4
    for (int rep = 0; rep < 16; ++rep) {
      int idx = rep * 256 + tid;
      int j = idx >> 6, q = idx & 63, ii = q >> 5, b = q & 31;
      bd[idx] += b_run[((size_t)j * I_ + i0 + ii) * 32 + b];
    }
    __syncthreads();
  }
  if (WRITEB) {
#pragma unroll 4
    for (int rep = 0; rep < 16; ++rep) {
      int idx = rep * 256 + tid;
      int j = idx >> 6, q = idx & 63, ii = q >> 5, b = q & 31;
      b_run[((size_t)j * I_ + i0 + ii) * 32 + b] = bd[idx];
    }
    __syncthreads();
  }

  // parallel softmax over j: thread (part = tid>>6) handles 16 j's of column q = tid&63
  {
    const int q = tid & 63, part = tid >> 6;
    const int jlo = part * 16;
    float m = -1e30f;
#pragma unroll
    for (int jj = 0; jj < 16; ++jj) m = fmaxf(m, bd[(jlo + jj) * 64 + q]);
    pm[part][q] = m;
    __syncthreads();
    const float M = fmaxf(fmaxf(pm[0][q], pm[1][q]), fmaxf(pm[2][q], pm[3][q]));
    float s = 0.f;
#pragma unroll
    for (int jj = 0; jj < 16; ++jj) {
      float e = __expf(bd[(jlo + jj) * 64 + q] - M);
      bd[(jlo + jj) * 64 + q] = e;
      s += e;
    }
    ps[part][q] = s;
    __syncthreads();
    const float inv = 1.0f / (ps[0][q] + ps[1][q] + ps[2][q] + ps[3][q]);
#pragma unroll
    for (int jj = 0; jj < 16; ++jj) c_l[(jlo + jj) * 64 + q] = f2bf(bd[(jlo + jj) * 64 + q] * inv);
  }
  __syncthreads();

  // cooperative write c_bf[j][i][b] (2048 u32)
#pragma unroll 4
  for (int rep = 0; rep < 8; ++rep) {
    int idx = rep * 256 + tid;
    int j = idx >> 5, q2 = idx & 31;
    unsigned val = (unsigned)c_l[j * 64 + 2 * q2] | ((unsigned)c_l[j * 64 + 2 * q2 + 1] << 16);
    *(unsigned*)(c_bf + ((size_t)j * I_ + i0) * 32 + 2 * q2) = val;
  }
}

// ---------------- pass B: partial S_j[b,c] per (slice, j) -- NO atomics ----------------
// wave: 16 i in 2 batches of 8 (batch-load then compute for memory-level parallelism)
template <int UNIFORM>
__global__ __launch_bounds__(256) void pass_s(const unsigned short* __restrict__ w_bf,
                                              const unsigned short* __restrict__ x4,
                                              const unsigned short* __restrict__ c_bf,
                                              float* __restrict__ gpart) {
  __shared__ float s_part[4][1024];  // [wave][b*32+c]
  const int tid = threadIdx.x, lane = tid & 63, wv = tid >> 6;
  const int j = blockIdx.y;
  const int slice = blockIdx.x;            // 32 slices
  const int ibase = slice * 64 + wv * 16;  // wave: 16 i
  const int ml = lane & 31, h = lane >> 5;
  f32x16 acc = 0.0f;

#pragma unroll
  for (int half = 0; half < 2; ++half) {
    const int i0 = ibase + half * 8;
    BF8 xa[8], wb[8];
    unsigned short cs[8];
    // issue all loads for the batch first (w: HBM stream; x4: L2; c_bf: L2/L3)
#pragma unroll
    for (int t = 0; t < 8; ++t) {
      const int i = i0 + t;
      xa[t].v = *(const bf16x8*)(x4 + (((size_t)i * 2 + h) * 32 + ml) * 8);
      wb[t].v = *(const bf16x8*)(w_bf + ((size_t)j * I_ + i) * 512 + ml * 16 + h * 8);
      if (!UNIFORM) cs[t] = c_bf[((size_t)j * I_ + i) * 32 + ml];
    }
#pragma unroll
    for (int t = 0; t < 8; ++t) {
      const float cf = UNIFORM ? (1.0f / 64.0f) : bf2f(cs[t]);
      BF8 ya;
#pragma unroll
      for (int p = 0; p < 4; ++p) {
        float lo = asf(xa[t].u[p] << 16);
        float hi = asf(xa[t].u[p] & 0xFFFF0000u);
        ya.u[p] = cvtpk(lo * cf, hi * cf);
      }
      acc = __builtin_amdgcn_mfma_f32_32x32x16_bf16(ya.v, wb[t].v, acc, 0, 0, 0);
    }
  }

  // acc[r] = S[b = (r&3)+8*(r>>2)+4h, c = ml] -> LDS, deterministic block reduce
#pragma unroll
  for (int r = 0; r < 16; ++r) {
    int b = (r & 3) + 8 * (r >> 2) + 4 * h;
    s_part[wv][b * 32 + ml] = acc[r];
  }
  __syncthreads();
#pragma unroll
  for (int q = 0; q < 4; ++q) {
    int idx = q * 256 + tid;  // idx = b*32+c
    float t = s_part[0][idx] + s_part[1][idx] + s_part[2][idx] + s_part[3][idx];
    int b = idx >> 5, c = idx & 31;
    gpart[(((size_t)slice * B_ + b) * J_ + j) * C_ + c] = t;
  }
}

// ---------------- deterministic reduce over slices + squash + v_bf emit ----------------
__global__ __launch_bounds__(256) void reduce_squash(const float* __restrict__ gpart,
                                                     unsigned short* __restrict__ v_bf,
                                                     float* __restrict__ outg,
                                                     int write_out) {
  const int gid = blockIdx.x * 256 + threadIdx.x;  // over B*J*C = 65536
  float sum = 0.f;
#pragma unroll
  for (int s = 0; s < 32; ++s) sum += gpart[(size_t)s * (B_ * J_ * C_) + gid];
  float t = sum + 1e-7f;
  float sq = t * t;
#pragma unroll
  for (int m = 16; m >= 1; m >>= 1) sq += __shfl_xor(sq, m);  // norm over c-group of 32
  const float scale = sq / (1.0f + sq) / sqrtf(sq);
  const float val = scale * t;
  v_bf[gid] = f2bf(val);  // [b][j][c] bf16 (bdot B-frag layout)
  if (write_out) outg[gid] = val;
}

// ---------------- squash (fallback path only) ----------------
__global__ __launch_bounds__(256) void caps_squash(const float* __restrict__ sg,
                                                   float* __restrict__ vg,
                                                   float* __restrict__ outg,
                                                   int write_out) {
  const int r = blockIdx.x * blockDim.x + threadIdx.x;
  if (r >= B_ * J_) return;
  const float* sp = sg + (size_t)r * C_;
  float vals[C_];
  float norm = 0.f;
#pragma unroll
  for (int cc = 0; cc < C_; ++cc) {
    float t = sp[cc] + 1e-7f;
    vals[cc] = t;
    norm += t * t;
  }
  const float scale = norm / (1.0f + norm) / sqrtf(norm);
  float* vp = vg + (size_t)r * C_;
#pragma unroll
  for (int cc = 0; cc < C_; ++cc) vp[cc] = scale * vals[cc];
  if (write_out) {
    float* op = outg + (size_t)r * C_;
#pragma unroll
    for (int cc = 0; cc < C_; ++cc) op[cc] = scale * vals[cc];
  }
}

// ================= fallback (round-2 proven) path =================
__device__ __forceinline__ float dot16(const float4* __restrict__ wp,
                                       float4 x0, float4 x1, float4 x2, float4 x3) {
  float4 a0 = wp[0], a1 = wp[1], a2 = wp[2], a3 = wp[3];
  float u = a0.x * x0.x + a0.y * x0.y + a0.z * x0.z + a0.w * x0.w;
  u += a1.x * x1.x + a1.y * x1.y + a1.z * x1.z + a1.w * x1.w;
  u += a2.x * x2.x + a2.y * x2.y + a2.z * x2.z + a2.w * x2.w;
  u += a3.x * x3.x + a3.y * x3.y + a3.z * x3.z + a3.w * x3.w;
  return u;
}

template <int UNIFORM, int READB, int WRITEB>
__global__ __launch_bounds__(256) void caps_pass(const float* __restrict__ x,
                                                 const float* __restrict__ w,
                                                 const float* __restrict__ vg,
                                                 float* __restrict__ bio,
                                                 float* __restrict__ sg) {
  __shared__ float s_acc[4][J_ * C_];
  const int tid = threadIdx.x;
  for (int idx = tid; idx < 4 * J_ * C_; idx += 256) ((float*)s_acc)[idx] = 0.f;
  __syncthreads();
  const int lane = tid & 63;
  const int wv = tid >> 6;
  const int b = blockIdx.y;
  const int h = lane >> 5;
  const int c = lane & 31;
  const int i0 = blockIdx.x * 64 + wv * 16;
  for (int ii = 0; ii < 16; ++ii) {
    const int i = i0 + ii;
    const float4* xp = (const float4*)(x + ((size_t)b * I_ + i) * D_);
    float4 x0 = xp[0], x1 = xp[1], x2 = xp[2], x3 = xp[3];
    float uk[32];
    float bk[32];
#pragma unroll
    for (int k = 0; k < 32; ++k) {
      const int j = 2 * k + h;
      const float4* wp = (const float4*)(w + (((size_t)j * I_ + i) * C_ + c) * D_);
      float u = dot16(wp, x0, x1, x2, x3);
      uk[k] = u;
      if (!UNIFORM) {
        float p = vg[(b * J_ + j) * C_ + c] * u;
        p += __shfl_xor(p, 16, 32);
        p += __shfl_xor(p, 8, 32);
        p += __shfl_xor(p, 4, 32);
        p += __shfl_xor(p, 2, 32);
        p += __shfl_xor(p, 1, 32);
        bk[k] = p;
      }
    }
    if (UNIFORM) {
#pragma unroll
      for (int k = 0; k < 32; ++k)
        s_acc[wv][(2 * k + h) * C_ + c] += uk[k] * (1.0f / (float)J_);
    } else {
      if (READB) {
        float breg = bio[((size_t)b * I_ + i) * J_ + lane];
#pragma unroll
        for (int k = 0; k < 32; ++k) bk[k] += __shfl(breg, 2 * k + h);
      }
      if (WRITEB) {
        float bsel = bk[0];
#pragma unroll
        for (int k = 1; k < 32; ++k) bsel = (c == k) ? bk[k] : bsel;
        bio[((size_t)b * I_ + i) * J_ + 2 * c + h] = bsel;
      }
      float m = bk[0];
#pragma unroll
      for (int k = 1; k < 32; ++k) m = fmaxf(m, bk[k]);
      m = fmaxf(m, __shfl_xor(m, 32));
      float sum = 0.f;
#pragma unroll
      for (int k = 0; k < 32; ++k) {
        bk[k] = __expf(bk[k] - m);
        sum += bk[k];
      }
      sum += __shfl_xor(sum, 32);
      const float inv = 1.0f / sum;
#pragma unroll
      for (int k = 0; k < 32; ++k)
        s_acc[wv][(2 * k + h) * C_ + c] += bk[k] * inv * uk[k];
    }
  }
  __syncthreads();
  for (int jc = tid; jc < J_ * C_; jc += 256) {
    float t = s_acc[0][jc] + s_acc[1][jc] + s_acc[2][jc] + s_acc[3][jc];
    atomicAdd(&sg[(size_t)b * J_ * C_ + jc], t);
  }
}

extern "C" void kernel_launch(void* const* d_in, const int* in_sizes, int n_in,
                              void* d_out, int out_size, void* d_ws, size_t ws_size,
                              hipStream_t stream) {
  const float* x = (const float*)d_in[0];  // [B, I, D]
  const float* w = (const float*)d_in[1];  // [J, I, C, D]
  float* out = (float*)d_out;              // [B, J, C]

  const size_t SZ_WBF = (size_t)J_ * I_ * C_ * D_ * 2;   // 128 MiB
  const size_t SZ_W2 = SZ_WBF;                           // 128 MiB
  const size_t SZ_X4 = (size_t)B_ * I_ * D_ * 2;         // 2 MiB
  const size_t SZ_CBF = (size_t)J_ * I_ * B_ * 2;        // 8 MiB
  const size_t SZ_BRUN = (size_t)J_ * I_ * B_ * 4;       // 16 MiB
  const size_t SZ_GP = (size_t)32 * B_ * J_ * C_ * 4;    // 8 MiB
  const size_t SZ_VBF = (size_t)B_ * J_ * C_ * 2;        // 128 KiB
  const size_t NEED = SZ_WBF + SZ_W2 + SZ_X4 + SZ_CBF + SZ_BRUN + SZ_GP + SZ_VBF;

  if (ws_size >= NEED) {
    char* p = (char*)d_ws;
    unsigned short* w_bf = (unsigned short*)p;  p += SZ_WBF;
    unsigned short* w2 = (unsigned short*)p;    p += SZ_W2;
    unsigned short* x4 = (unsigned short*)p;    p += SZ_X4;
    unsigned short* c_bf = (unsigned short*)p;  p += SZ_CBF;
    float* b_run = (float*)p;                   p += SZ_BRUN;
    float* gpart = (float*)p;                   p += SZ_GP;
    unsigned short* v_bf = (unsigned short*)p;

    prep_w<<<dim3(I_ / 16, J_), 256, 0, stream>>>(w, w_bf, w2);
    prep_x4<<<dim3((B_ * I_ * 2) / 256), 256, 0, stream>>>(x, x4);

    dim3 agrid(I_ / 2), bgrid(32, J_), rgrid((B_ * J_ * C_) / 256);

    // it 0: uniform c
    pass_s<1><<<bgrid, 256, 0, stream>>>(w_bf, x4, c_bf, gpart);
    reduce_squash<<<rgrid, 256, 0, stream>>>(gpart, v_bf, out, 0);
    // it 1: b1 = v0.u (no prior b)
    pass_bdot<0, 1><<<agrid, 256, 0, stream>>>(x, w2, v_bf, b_run, c_bf);
    pass_s<0><<<bgrid, 256, 0, stream>>>(w_bf, x4, c_bf, gpart);
    reduce_squash<<<rgrid, 256, 0, stream>>>(gpart, v_bf, out, 0);
    // it 2
    pass_bdot<1, 1><<<agrid, 256, 0, stream>>>(x, w2, v_bf, b_run, c_bf);
    pass_s<0><<<bgrid, 256, 0, stream>>>(w_bf, x4, c_bf, gpart);
    reduce_squash<<<rgrid, 256, 0, stream>>>(gpart, v_bf, out, 0);
    // it 3
    pass_bdot<1, 1><<<agrid, 256, 0, stream>>>(x, w2, v_bf, b_run, c_bf);
    pass_s<0><<<bgrid, 256, 0, stream>>>(w_bf, x4, c_bf, gpart);
    reduce_squash<<<rgrid, 256, 0, stream>>>(gpart, v_bf, out, 0);
    // it 4 (no b write-back; write output)
    pass_bdot<1, 0><<<agrid, 256, 0, stream>>>(x, w2, v_bf, b_run, c_bf);
    pass_s<0><<<bgrid, 256, 0, stream>>>(w_bf, x4, c_bf, gpart);
    reduce_squash<<<rgrid, 256, 0, stream>>>(gpart, v_bf, out, 1);
  } else {
    // fallback: round-2 proven path (~7.5 ms but correct)
    float* b_ws = (float*)d_ws;
    float* s_ws = b_ws + (size_t)B_ * I_ * J_;
    float* v_ws = s_ws + (size_t)B_ * J_ * C_;
    const size_t s_bytes = (size_t)B_ * J_ * C_ * sizeof(float);
    dim3 grid(I_ / 64, B_), blk(256);
    dim3 sgrid((B_ * J_ + 255) / 256), sblk(256);

    hipMemsetAsync(s_ws, 0, s_bytes, stream);
    caps_pass<1, 0, 0><<<grid, blk, 0, stream>>>(x, w, v_ws, b_ws, s_ws);
    caps_squash<<<sgrid, sblk, 0, stream>>>(s_ws, v_ws, out, 0);
    hipMemsetAsync(s_ws, 0, s_bytes, stream);
    caps_pass<0, 0, 1><<<grid, blk, 0, stream>>>(x, w, v_ws, b_ws, s_ws);
    caps_squash<<<sgrid, sblk, 0, stream>>>(s_ws, v_ws, out, 0);
    hipMemsetAsync(s_ws, 0, s_bytes, stream);
    caps_pass<0, 1, 1><<<grid, blk, 0, stream>>>(x, w, v_ws, b_ws, s_ws);
    caps_squash<<<sgrid, sblk, 0, stream>>>(s_ws, v_ws, out, 0);
    hipMemsetAsync(s_ws, 0, s_bytes, stream);
    caps_pass<0, 1, 1><<<grid, blk, 0, stream>>>(x, w, v_ws, b_ws, s_ws);
    caps_squash<<<sgrid, sblk, 0, stream>>>(s_ws, v_ws, out, 0);
    hipMemsetAsync(s_ws, 0, s_bytes, stream);
    caps_pass<0, 1, 0><<<grid, blk, 0, stream>>>(x, w, v_ws, b_ws, s_ws);
    caps_squash<<<sgrid, sblk, 0, stream>>>(s_ws, v_ws, out, 1);
  }
}